// Round 1
// baseline (44.286 us; speedup 1.0000x reference)
//
#include <hip/hip_runtime.h>
#include <stdint.h>

// Problem dims (fixed by reference)
#define D_DIM    768
#define K_STATES 128
#define M_ROWS   65536      // B*T = 256*256
#define BM       128        // rows per block
#define BK       32         // D-chunk per K-step
#define NSTEPS   (D_DIM / BK)   // 24
#define LDSTRIDE 40         // bf16 elems per LDS row: 80B, 16B-aligned, bank-even

typedef __attribute__((ext_vector_type(8))) short bf16x8;
typedef __attribute__((ext_vector_type(4))) float f32x4;
typedef __attribute__((ext_vector_type(4))) int   i32x4;

__device__ __forceinline__ unsigned short f2bf(float f) {
    union { float f; unsigned u; } x; x.f = f;
    unsigned r = (x.u + 0x7FFFu + ((x.u >> 16) & 1u)) >> 16;   // RNE
    return (unsigned short)r;
}

// ---------------- prep: mw[k][d] = means*inv_var (bf16), c[k] = log_norm - 0.5*m2[k]
__global__ void __launch_bounds__(256) prep_kernel(
        const float* __restrict__ means, const float* __restrict__ var,
        unsigned short* __restrict__ mwbf, float* __restrict__ cvec) {
    const int k = blockIdx.x;
    const int t = threadIdx.x;
    float m2 = 0.f, ld = 0.f;
    for (int d = t; d < D_DIM; d += 256) {
        float v  = var[d];
        float iv = 1.0f / v;
        float m  = means[k * D_DIM + d];
        mwbf[k * D_DIM + d] = f2bf(m * iv);
        m2 += m * m * iv;
        ld += logf(v);
    }
#pragma unroll
    for (int off = 32; off > 0; off >>= 1) {
        m2 += __shfl_down(m2, off, 64);
        ld += __shfl_down(ld, off, 64);
    }
    __shared__ float rm[4], rl[4];
    const int wid = t >> 6;
    if ((t & 63) == 0) { rm[wid] = m2; rl[wid] = ld; }
    __syncthreads();
    if (t == 0) {
        float M2 = rm[0] + rm[1] + rm[2] + rm[3];
        float LD = rl[0] + rl[1] + rl[2] + rl[3];
        cvec[k] = -0.5f * ((float)D_DIM * 1.8378770664093453f + LD + M2);
    }
}

// ---------------- main: out[bt][k] = cross + c[k] - 0.5*s2[bt]
__global__ void __launch_bounds__(256) dmv_main(
        const float* __restrict__ s, const unsigned short* __restrict__ mwbf,
        const float* __restrict__ var, const float* __restrict__ cvec,
        float* __restrict__ out) {
    __shared__ unsigned short As[2][BM * LDSTRIDE];        // 2 x 10.0 KB bf16 s-tile
    __shared__ unsigned short Bs[2][K_STATES * LDSTRIDE];  // 2 x 10.0 KB bf16 mw-tile
    __shared__ float ivs[D_DIM];                           // 3 KB
    __shared__ float part[BM][8];                          // s2 partials
    __shared__ float s2row[BM];
    __shared__ float cs[K_STATES];

    const int t    = threadIdx.x;
    const int lane = t & 63;
    const int w    = t >> 6;
    const int wr   = w >> 1;      // wave row quadrant (0/1)
    const int wc   = w & 1;       // wave col quadrant (0/1)
    const long rowBase = (long)blockIdx.x * BM;

    for (int d = t; d < D_DIM; d += 256) ivs[d] = 1.0f / var[d];
    if (t < K_STATES) cs[t] = cvec[t];

    // staging geometry per K-step:
    // A: 4 rounds, round j: row = j*32 + (t>>3), cols (t&7)*4 .. +3  (f32x4)
    // B: 2 rounds, round j: row = j*64 + (t>>2), cols (t&3)*8 .. +7  (bf16x8 raw)
    const int arow0 = t >> 3;
    const int acol  = (t & 7) * 4;
    const int brow0 = t >> 2;
    const int bcol  = (t & 3) * 8;

    const float*          sA = s    + (rowBase + arow0) * D_DIM + acol;
    const unsigned short* sB = mwbf + brow0 * D_DIM + bcol;

    f32x4 aPref[4];
    i32x4 bPref[2];
    float s2acc[4] = {0.f, 0.f, 0.f, 0.f};

    f32x4 acc[4][4];
#pragma unroll
    for (int i = 0; i < 4; ++i)
#pragma unroll
        for (int j = 0; j < 4; ++j) acc[i][j] = f32x4{0.f, 0.f, 0.f, 0.f};

    auto stageWrite = [&](int buf, int k0) {
#pragma unroll
        for (int j = 0; j < 4; ++j) {
            const int row = j * 32 + arow0;
            f32x4 v = aPref[j];
            s2acc[j] += v[0]*v[0]*ivs[k0+acol+0] + v[1]*v[1]*ivs[k0+acol+1]
                      + v[2]*v[2]*ivs[k0+acol+2] + v[3]*v[3]*ivs[k0+acol+3];
            unsigned u0 = (unsigned)f2bf(v[0]) | ((unsigned)f2bf(v[1]) << 16);
            unsigned u1 = (unsigned)f2bf(v[2]) | ((unsigned)f2bf(v[3]) << 16);
            *reinterpret_cast<uint2*>(&As[buf][row * LDSTRIDE + acol]) = make_uint2(u0, u1);
        }
#pragma unroll
        for (int j = 0; j < 2; ++j) {
            const int row = j * 64 + brow0;
            *reinterpret_cast<i32x4*>(&Bs[buf][row * LDSTRIDE + bcol]) = bPref[j];
        }
    };

    // prologue: global loads for step 0 (no LDS dependence yet)
#pragma unroll
    for (int j = 0; j < 4; ++j) aPref[j] = *(const f32x4*)(sA + (long)j * 32 * D_DIM);
#pragma unroll
    for (int j = 0; j < 2; ++j) bPref[j] = *(const i32x4*)(sB + j * 64 * D_DIM);
    __syncthreads();             // ivs/cs ready
    stageWrite(0, 0);

    const int g  = (lane >> 4) * 8;          // k-offset within BK
    const int rA = wr * 64 + (lane & 15);
    const int rB = wc * 64 + (lane & 15);

    for (int st = 0; st < NSTEPS; ++st) {
        const int cur = st & 1;
        const int k0n = (st + 1) * BK;
        if (st + 1 < NSTEPS) {
#pragma unroll
            for (int j = 0; j < 4; ++j)
                aPref[j] = *(const f32x4*)(sA + (long)j * 32 * D_DIM + k0n);
#pragma unroll
            for (int j = 0; j < 2; ++j)
                bPref[j] = *(const i32x4*)(sB + j * 64 * D_DIM + k0n);
        }
        __syncthreads();         // buf[cur] staged & prior reads drained

        const unsigned short* Ab = &As[cur][0];
        const unsigned short* Bb = &Bs[cur][0];
        bf16x8 afrag[4], bfrag[4];
#pragma unroll
        for (int i = 0; i < 4; ++i)
            afrag[i] = *(const bf16x8*)(Ab + (rA + i * 16) * LDSTRIDE + g);
#pragma unroll
        for (int j = 0; j < 4; ++j)
            bfrag[j] = *(const bf16x8*)(Bb + (rB + j * 16) * LDSTRIDE + g);
#pragma unroll
        for (int i = 0; i < 4; ++i)
#pragma unroll
            for (int j = 0; j < 4; ++j)
                acc[i][j] = __builtin_amdgcn_mfma_f32_16x16x32_bf16(
                                afrag[i], bfrag[j], acc[i][j], 0, 0, 0);

        if (st + 1 < NSTEPS) stageWrite((st + 1) & 1, k0n);
    }

    // s2 reduction: each thread owns rows {j*32 + (t>>3)}, col-slot t&7
#pragma unroll
    for (int j = 0; j < 4; ++j) part[j * 32 + arow0][t & 7] = s2acc[j];
    __syncthreads();
    if (t < BM) {
        float v = 0.f;
#pragma unroll
        for (int sl = 0; sl < 8; ++sl) v += part[t][sl];
        s2row[t] = v;
    }
    __syncthreads();

    // epilogue: C/D layout col = lane&15, row = (lane>>4)*4 + reg  [m89/m91-verified]
    const int colBase = wc * 64 + (lane & 15);
#pragma unroll
    for (int i = 0; i < 4; ++i) {
        const int rl0 = wr * 64 + i * 16 + (lane >> 4) * 4;
#pragma unroll
        for (int j = 0; j < 4; ++j) {
            const int col = colBase + j * 16;
            const float cj = cs[col];
#pragma unroll
            for (int r = 0; r < 4; ++r) {
                const int rl = rl0 + r;
                out[(rowBase + rl) * K_STATES + col] = acc[i][j][r] + cj - 0.5f * s2row[rl];
            }
        }
    }
}

extern "C" void kernel_launch(void* const* d_in, const int* in_sizes, int n_in,
                              void* d_out, int out_size, void* d_ws, size_t ws_size,
                              hipStream_t stream) {
    const float* s     = (const float*)d_in[0];
    const float* means = (const float*)d_in[1];
    const float* var   = (const float*)d_in[2];
    float* out = (float*)d_out;

    unsigned short* mwbf = (unsigned short*)d_ws;
    float* cvec = (float*)((char*)d_ws + (size_t)K_STATES * D_DIM * sizeof(unsigned short));

    prep_kernel<<<K_STATES, 256, 0, stream>>>(means, var, mwbf, cvec);
    dmv_main<<<M_ROWS / BM, 256, 0, stream>>>(s, mwbf, var, cvec, out);
}